// Round 10
// baseline (362.660 us; speedup 1.0000x reference)
//
#include <hip/hip_runtime.h>
#include <math.h>

#define BB 8
#define PP 5
#define QQ 75
#define CC 640
#define HW 49
#define NIMG_Q (BB*QQ)     // 600
#define NIMG_S (BB*PP)     // 40
#define NPROB  (BB*QQ*PP)  // 3000
#define TEMP 12.5f

#define CHUNKS 20          // 640 / 32
#define TROW 16            // u32 per tile row (32 f16)
#define TCH  (HW*TROW)     // 784 u32 per chunk
#define TIMG (CHUNKS*TCH)  // 15680 u32 per image
#define SROW 25            // u32 per S row (50 f16, last is zero pad)
#define SPROB (HW*SROW)    // 1225 u32 per problem

// workspace layout (u32/float offsets); total ~14.48M words = 57.9 MB
#define OFF_SGAP   0
#define OFF_QGAP   (OFF_SGAP  + NIMG_S*CC)
#define OFF_SMEAN  (OFF_QGAP  + NIMG_Q*CC)
#define OFF_SINV   (OFF_SMEAN + NIMG_S*HW)
#define OFF_QMEAN  (OFF_SINV  + NIMG_S*HW)
#define OFF_QINV   (OFF_QMEAN + NIMG_Q*HW)
#define OFF_MARGA  (OFF_QINV  + NIMG_Q*HW)
#define OFF_MARGB  (OFF_MARGA + NPROB*HW)
#define OFF_QT     (OFF_MARGB + NPROB*HW)          // query f16 tiles
#define OFF_ST     (OFF_QT    + NIMG_Q*TIMG)       // support f16 tiles
#define OFF_S16    (OFF_ST    + NIMG_S*TIMG)       // S matrices, f16 packed
#define OFF_LOGITS (OFF_S16   + NPROB*SPROB)

typedef _Float16 f16x8 __attribute__((ext_vector_type(8)));
typedef float f32x4 __attribute__((ext_vector_type(4)));
#define MFMAH __builtin_amdgcn_mfma_f32_16x16x32_f16

__device__ __forceinline__ float wsum64(float v) {
#pragma unroll
    for (int off = 32; off > 0; off >>= 1) v += __shfl_xor(v, off, 64);
    return v;
}
__device__ __forceinline__ float rlf(float x, int l) {
    return __int_as_float(__builtin_amdgcn_readlane(__float_as_int(x), l));
}
__device__ __forceinline__ unsigned packh2(float a, float b) {
    union { _Float16 h[2]; unsigned u; } pk;
    pk.h[0] = (_Float16)a; pk.h[1] = (_Float16)b;
    return pk.u;
}
__device__ __forceinline__ float f16lo(unsigned w) {
    union { unsigned short s; _Float16 h; } u; u.s = (unsigned short)w; return (float)u.h;
}
__device__ __forceinline__ float f16hi(unsigned w) {
    union { unsigned short s; _Float16 h; } u; u.s = (unsigned short)(w >> 16); return (float)u.h;
}

// ---------------- Kernel 1: support prep ----------------
// R6 structure: R4 flow + waves_per_eu(4,4) + deep load batches (MLP).
__global__ __launch_bounds__(512) __attribute__((amdgpu_waves_per_eu(4, 4)))
void sup_prep(const float* __restrict__ sup, float* __restrict__ ws) {
    int img = blockIdx.x;
    int tid = threadIdx.x;
    int lane = tid & 63;
    int wv = tid >> 6;                 // 0..7
    const float* X = sup + (size_t)img * CC * HW;
    float* gap = ws + OFF_SGAP + img * CC;

    __shared__ float cs_p[8][52], sq_p[8][52];
    __shared__ float muL[52], invL[52];
    float cs = 0.f, sq = 0.f;
    if (lane < HW) {
        for (int c8 = wv * 80; c8 < wv * 80 + 80; c8 += 8) {
            float v[8];
#pragma unroll
            for (int j = 0; j < 8; j++) v[j] = X[(c8 + j) * HW + lane];
#pragma unroll
            for (int j = 0; j < 8; j++) {
                cs += v[j];
                sq = fmaf(v[j], v[j], sq);
            }
        }
    }
    if (lane < 52) {
        cs_p[wv][lane] = (lane < HW) ? cs : 0.f;
        sq_p[wv][lane] = (lane < HW) ? sq : 0.f;
    }
    __syncthreads();
    if (wv == 0 && lane < HW) {
        float c4 = 0.f, s4 = 0.f;
#pragma unroll
        for (int w = 0; w < 8; w++) { c4 += cs_p[w][lane]; s4 += sq_p[w][lane]; }
        float mu = c4 * (1.0f / CC);
        float nsq = fmaxf(s4 - c4 * c4 * (1.0f / CC), 0.f);
        float inv = 1.0f / fmaxf(sqrtf(nsq), 1e-8f);
        ws[OFF_SMEAN + img * HW + lane] = mu;
        ws[OFF_SINV + img * HW + lane] = inv;
        muL[lane] = mu;
        invL[lane] = inv;
    }
    // pass B: GAP (L1/L2-hot re-read), 8-deep batched, m-order preserved
    for (int c = tid; c < CC; c += 512) {
        const float* row = X + c * HW;
        float s = 0.f;
#pragma unroll
        for (int g = 0; g < 6; g++) {
            float rv[8];
#pragma unroll
            for (int j = 0; j < 8; j++) rv[j] = row[g * 8 + j];
#pragma unroll
            for (int j = 0; j < 8; j++) s += rv[j];
        }
        s += row[48];
        gap[c] = s * (1.0f / HW);
    }
    __syncthreads();
    // pass C: f16 tiles, 32-deep batched loads + uint4 stores
    unsigned* T = (unsigned*)ws + OFF_ST + (size_t)img * TIMG;
    int m = lane;
    if (m < HW) {
        float mu = muL[m], inv = invL[m];
        for (int t = wv; t < CHUNKS; t += 8) {
            float va[32];
#pragma unroll
            for (int j = 0; j < 32; j++) va[j] = X[(t * 32 + j) * HW + m];
            unsigned pk[16];
#pragma unroll
            for (int w = 0; w < 16; w++)
                pk[w] = packh2((va[2 * w] - mu) * inv, (va[2 * w + 1] - mu) * inv);
            uint4* dst = (uint4*)(T + t * TCH + m * TROW);
#pragma unroll
            for (int u = 0; u < 4; u++)
                dst[u] = make_uint4(pk[4 * u], pk[4 * u + 1], pk[4 * u + 2], pk[4 * u + 3]);
        }
    }
}

// ---------------- Kernel 2: query prep ----------------
// sg panel (5x640 = 12.8 KB) staged in LDS once; pass-A 16-deep batched.
__global__ __launch_bounds__(512) __attribute__((amdgpu_waves_per_eu(4, 4)))
void qry_prep(const float* __restrict__ qry, float* __restrict__ ws) {
    int img = blockIdx.x;            // = bq
    int b = img / QQ;
    int tid = threadIdx.x;
    int lane = tid & 63;
    int wv = tid >> 6;               // 0..7
    const float* X = qry + (size_t)img * CC * HW;
    const float* sg = ws + OFF_SGAP + b * PP * CC;
    float* gap = ws + OFF_QGAP + img * CC;

    __shared__ float XSG[PP * CC];   // 12.8 KB
    __shared__ float cs_p[8][52], sq_p[8][52];
    __shared__ float part[8][PP][52];
    __shared__ float muL[52], invL[52];

    for (int i = tid; i < PP * CC / 4; i += 512)
        ((float4*)XSG)[i] = ((const float4*)sg)[i];
    __syncthreads();

    float cs = 0.f, sq = 0.f;
    float acc[PP] = {0.f, 0.f, 0.f, 0.f, 0.f};
    if (lane < HW) {
        for (int c8 = wv * 80; c8 < wv * 80 + 80; c8 += 16) {
            float v[16];
#pragma unroll
            for (int j = 0; j < 16; j++) v[j] = X[(c8 + j) * HW + lane];
#pragma unroll
            for (int j = 0; j < 16; j++) {
                cs += v[j];
                sq = fmaf(v[j], v[j], sq);
            }
#pragma unroll
            for (int p = 0; p < PP; p++) {
                float a = acc[p];
#pragma unroll
                for (int qv = 0; qv < 4; qv++) {
                    float4 g0 = *(const float4*)&XSG[p * CC + c8 + 4 * qv];
                    a = fmaf(v[4 * qv + 0], g0.x, a);
                    a = fmaf(v[4 * qv + 1], g0.y, a);
                    a = fmaf(v[4 * qv + 2], g0.z, a);
                    a = fmaf(v[4 * qv + 3], g0.w, a);
                }
                acc[p] = a;
            }
        }
    }
    if (lane < 52) {
        cs_p[wv][lane] = (lane < HW) ? cs : 0.f;
        sq_p[wv][lane] = (lane < HW) ? sq : 0.f;
#pragma unroll
        for (int p = 0; p < PP; p++) part[wv][p][lane] = (lane < HW) ? acc[p] : 0.f;
    }
    __syncthreads();
    if (wv == 0) {
        if (lane < HW) {
            float c4 = 0.f, s4 = 0.f;
#pragma unroll
            for (int w = 0; w < 8; w++) { c4 += cs_p[w][lane]; s4 += sq_p[w][lane]; }
            float mu = c4 * (1.0f / CC);
            float nsq = fmaxf(s4 - c4 * c4 * (1.0f / CC), 0.f);
            float inv = 1.0f / fmaxf(sqrtf(nsq), 1e-8f);
            ws[OFF_QMEAN + img * HW + lane] = mu;
            ws[OFF_QINV + img * HW + lane] = inv;
            muL[lane] = mu;
            invL[lane] = inv;
        }
#pragma unroll
        for (int p = 0; p < PP; p++) {
            float a = 0.f;
            if (lane < 52) {
#pragma unroll
                for (int w = 0; w < 8; w++) a += part[w][p][lane];
            }
            float w = (lane < HW) ? (fmaxf(a, 0.f) + 1.01e-3f) : 0.f;
            float s = wsum64(w);
            if (lane < HW) ws[OFF_MARGA + (img * PP + p) * HW + lane] = w / s;
        }
    }
    // pass B: GAP, 8-deep batched
    for (int c = tid; c < CC; c += 512) {
        const float* row = X + c * HW;
        float s = 0.f;
#pragma unroll
        for (int g = 0; g < 6; g++) {
            float rv[8];
#pragma unroll
            for (int j = 0; j < 8; j++) rv[j] = row[g * 8 + j];
#pragma unroll
            for (int j = 0; j < 8; j++) s += rv[j];
        }
        s += row[48];
        gap[c] = s * (1.0f / HW);
    }
    __syncthreads();
    // pass C: f16 tiles, 32-deep batched
    unsigned* T = (unsigned*)ws + OFF_QT + (size_t)img * TIMG;
    int m = lane;
    if (m < HW) {
        float mu = muL[m], inv = invL[m];
        for (int t = wv; t < CHUNKS; t += 8) {
            float va[32];
#pragma unroll
            for (int j = 0; j < 32; j++) va[j] = X[(t * 32 + j) * HW + m];
            unsigned pk[16];
#pragma unroll
            for (int w = 0; w < 16; w++)
                pk[w] = packh2((va[2 * w] - mu) * inv, (va[2 * w + 1] - mu) * inv);
            uint4* dst = (uint4*)(T + t * TCH + m * TROW);
#pragma unroll
            for (int u = 0; u < 4; u++)
                dst[u] = make_uint4(pk[4 * u], pk[4 * u + 1], pk[4 * u + 2], pk[4 * u + 3]);
        }
    }
}

// ---------------- Kernel 3: col marginals b (support side, w2) ----------------
// QG panel (15x640 = 38.4 KB) staged in LDS; sv 8-deep batched.
__global__ __launch_bounds__(256) __attribute__((amdgpu_waves_per_eu(2, 4)))
void margb_kernel(const float* __restrict__ sup, float* __restrict__ ws) {
    int id = blockIdx.x;
    int qc = id % 5;
    int bp = id / 5;
    int b = bp / PP;
    int p = bp % PP;
    int tid = threadIdx.x;
    int lane = tid & 63;
    int wv = tid >> 6;
    const float* X = sup + (size_t)bp * CC * HW;
    const float* qg = ws + OFF_QGAP + (b * QQ + qc * 15) * CC;

    __shared__ float QG[15 * CC];     // 38.4 KB
    __shared__ float part[4][15][52];
    for (int i = tid; i < 15 * CC / 4; i += 256)
        ((float4*)QG)[i] = ((const float4*)qg)[i];
    __syncthreads();

    float acc[15];
#pragma unroll
    for (int i = 0; i < 15; i++) acc[i] = 0.f;
    if (lane < HW) {
        for (int c8 = wv * 160; c8 < wv * 160 + 160; c8 += 8) {
            float sv[8];
#pragma unroll
            for (int j = 0; j < 8; j++) sv[j] = X[(c8 + j) * HW + lane];
#pragma unroll
            for (int qq = 0; qq < 15; qq++) {
                float4 g0 = *(const float4*)&QG[qq * CC + c8];
                float4 g1 = *(const float4*)&QG[qq * CC + c8 + 4];
                float a = acc[qq];
                a = fmaf(sv[0], g0.x, a); a = fmaf(sv[1], g0.y, a);
                a = fmaf(sv[2], g0.z, a); a = fmaf(sv[3], g0.w, a);
                a = fmaf(sv[4], g1.x, a); a = fmaf(sv[5], g1.y, a);
                a = fmaf(sv[6], g1.z, a); a = fmaf(sv[7], g1.w, a);
                acc[qq] = a;
            }
        }
    }
    if (lane < 52) {
#pragma unroll
        for (int qq = 0; qq < 15; qq++) part[wv][qq][lane] = (lane < HW) ? acc[qq] : 0.f;
    }
    __syncthreads();
    if (wv == 0) {
#pragma unroll
        for (int qq = 0; qq < 15; qq++) {
            float a = 0.f;
            if (lane < 52)
                a = part[0][qq][lane] + part[1][qq][lane] + part[2][qq][lane] + part[3][qq][lane];
            int q = qc * 15 + qq;
            float w = (lane < HW) ? (fmaxf(a, 0.f) + 1.01e-3f) : 0.f;
            float s = wsum64(w);
            if (lane < HW) ws[OFF_MARGB + ((b * QQ + q) * PP + p) * HW + lane] = w / s;
        }
    }
}

// ---------------- Kernel 4a: MFMA S-GEMM, B tile LDS-staged, 5 queries/block --
__global__ __launch_bounds__(256, 2) void gemm_kernel(float* __restrict__ ws) {
    __shared__ unsigned LDSU[CHUNKS * TCH];   // 15680 u32 = 62.7 KB; reused for S stage

    // XCD-bijective map: the 5 p-blocks sharing one query-group land on one XCD.
    int g = blockIdx.x;                // 0..599
    int xcd = g & 7;
    int k = g >> 3;                    // 0..74
    int p = k % 5;
    int gidx = xcd + 8 * (k / 5);      // 0..119  (b,qg) group
    int b = gidx / 15;
    int qg = gidx - b * 15;            // query group: queries qg*5 .. qg*5+4

    int tid = threadIdx.x;
    int lane = tid & 63;
    int wv = tid >> 6;
    int lrow = lane & 15;
    int quad = lane >> 4;

    // ---- stage B tile (support) into LDS, swizzled ----
    const unsigned* Bt = (const unsigned*)ws + OFF_ST + (size_t)(b * PP + p) * TIMG;
    for (int idx = tid; idx < CHUNKS * HW * 4; idx += 256) {   // 3920 x 16B
        int r = idx >> 2;              // row 0..979 (t*49+n)
        int q = idx & 3;               // 16B slot in row
        int t = r / 49;
        int n = r - t * 49;
        uint4 v = *(const uint4*)(Bt + (idx << 2));
        *(uint4*)(&LDSU[t * TCH + n * 16 + ((q ^ ((n >> 1) & 3)) << 2)]) = v;
    }
    __syncthreads();

    // per-nt swizzled LDS offsets (clamped rows >48 broadcast row 48: free)
    int bof[4];
#pragma unroll
    for (int nt = 0; nt < 4; nt++) {
        int n = 16 * nt + lrow;
        if (n > 48) n = 48;
        bof[nt] = n * 16 + ((quad ^ ((n >> 1) & 3)) << 2);
    }

    const unsigned* Aq = (const unsigned*)ws + OFF_QT + (size_t)(b * QQ + qg * 5) * TIMG;
    int arow = (16 * wv + lrow) * TROW + quad * 4;

    f32x4 acc[5][4];
#pragma unroll
    for (int qi = 0; qi < 5; qi++)
#pragma unroll
        for (int nt = 0; nt < 4; nt++) acc[qi][nt] = (f32x4){0.f, 0.f, 0.f, 0.f};

#pragma unroll 2
    for (int t = 0; t < CHUNKS; t++) {
        f16x8 bfr[4];
#pragma unroll
        for (int nt = 0; nt < 4; nt++)
            bfr[nt] = *(const f16x8*)(&LDSU[t * TCH + bof[nt]]);
#pragma unroll
        for (int qi = 0; qi < 5; qi++) {
            f16x8 a = *(const f16x8*)(Aq + (size_t)qi * TIMG + t * TCH + arow);
#pragma unroll
            for (int nt = 0; nt < 4; nt++)
                acc[qi][nt] = MFMAH(a, bfr[nt], acc[qi][nt], 0, 0, 0);
        }
    }

    // ---- epilogue: stage S in LDS (reuse B area), pack f16, write ----
    __syncthreads();                       // all B reads done
    float* S_lds = (float*)LDSU;           // 5 * 49*53 = 12985 f32 < 15680
    // C/D layout: col = lane&15, row = quad*4 + reg (dtype-independent, m89)
#pragma unroll
    for (int qi = 0; qi < 5; qi++)
#pragma unroll
        for (int nt = 0; nt < 4; nt++)
#pragma unroll
            for (int r = 0; r < 4; r++) {
                int mm = 16 * wv + quad * 4 + r;
                int nn = 16 * nt + lrow;
                if (mm < HW && nn < HW) S_lds[qi * 2597 + mm * 53 + nn] = acc[qi][nt][r];
            }
    __syncthreads();

    for (int qi = 0; qi < 5; qi++) {
        int prob = (b * QQ + qg * 5 + qi) * PP + p;
        unsigned* Sp = (unsigned*)ws + OFF_S16 + (size_t)prob * SPROB;
        const float* Sl = S_lds + qi * 2597;
        for (int idx = tid; idx < SPROB; idx += 256) {
            int row = idx / SROW;
            int w = idx - row * SROW;
            int n0 = 2 * w;
            float v0 = Sl[row * 53 + n0];
            float v1 = (n0 + 1 < HW) ? Sl[row * 53 + n0 + 1] : 0.f;
            Sp[idx] = packh2(v0, v1);
        }
    }
}

// ---------------- Kernel 4b: Sinkhorn + logit, TWO waves per problem ----------
// R10: R8/R9 proved the 1-wave structure's extra ~110 VALU ops/iter are
// register-file traffic for the 98 live K-values (opq pinning changed
// nothing: VGPR stayed 68, values live in the unified-file AGPR side).
// Split the summation index across 2 waves: wave w owns k in [25w,25w+25)
// of K rows (krw) and rows l in [25w,25w+25) of K^T (ktw) -- ~50 pinned
// values, fits arch VGPRs. Partials exchanged via LDS (2 barriers/iter);
// u,v computed redundantly in both waves from identical inputs (bitwise
// consistent). Dummy slot k=l=49 hard-zeroed. Numeric drift: partial-sum
// order only (threshold 0.032, step 0.004 -- ample margin).
#define KEXPF(s) __expf(fmaf(20.f, (s), -20.f))

__global__ __launch_bounds__(128)
__attribute__((amdgpu_waves_per_eu(4, 4)))
void sinkhorn_kernel(float* __restrict__ ws) {
    __shared__ float TP[2][52];    // t-phase partials
    __shared__ float SPx[2][52];   // s-phase partials
    int prob = blockIdx.x;
    int tid = threadIdx.x;
    int lane = tid & 63;
    int wv = tid >> 6;             // 0,1
    int KB = wv * 25;              // summation base for this wave
    const unsigned* Sp = (const unsigned*)ws + OFF_S16 + (size_t)prob * SPROB;

    float am = 0.f, bm = 0.f;
    if (lane < HW) {
        am = ws[OFF_MARGA + prob * HW + lane];
        bm = ws[OFF_MARGB + prob * HW + lane];
    }
    int ll = (lane < HW) ? lane : 48;
    const unsigned* rbase = Sp + ll * SROW;   // row ll of S (f16 pairs)
    int wof = ll >> 1;
    int sh = (ll & 1) * 16;

    // K slices: krw[j] = K[ll][KB+j] (row slice); ktw[j] = K[KB+j][lane] (col slice)
    float krw[25], ktw[25];
#pragma unroll
    for (int j = 0; j < 25; j++) {
        int k = KB + j;
        int kc = (k < HW) ? k : 0;
        float sv = f16lo((rbase[kc >> 1] >> ((kc & 1) * 16)) & 0xFFFFu);
        krw[j] = (k < HW) ? KEXPF(sv) : 0.f;
        float tv = f16lo((Sp[kc * SROW + wof] >> sh) & 0xFFFFu);
        ktw[j] = (k < HW) ? KEXPF(tv) : 0.f;
    }

    float vv = (lane < HW) ? 1.f : 0.f;
    float uu = 0.f;

#pragma unroll 1
    for (int it = 0; it < 48; it++) {
        // RS partial: t_w[l] = sum_{k in H_w} K[l][k] v[k]
        float t0 = 0.f, t1 = 0.f, t2 = 0.f, t3 = 0.f;
#pragma unroll
        for (int j = 0; j < 25; j++) {
            float pv = rlf(vv, KB + j);
            if ((j & 3) == 0)      t0 = fmaf(krw[j], pv, t0);
            else if ((j & 3) == 1) t1 = fmaf(krw[j], pv, t1);
            else if ((j & 3) == 2) t2 = fmaf(krw[j], pv, t2);
            else                   t3 = fmaf(krw[j], pv, t3);
        }
        if (lane < HW) TP[wv][lane] = (t0 + t1) + (t2 + t3);
        __syncthreads();
        float t = TP[0][ll] + TP[1][ll];
        uu = (lane < HW) ? am * __builtin_amdgcn_rcpf(t) : 0.f;

        // CS partial: s_w[k] = sum_{l in L_w} K[l][k] u[l]
        float s0 = 0.f, s1 = 0.f, s2 = 0.f, s3 = 0.f;
#pragma unroll
        for (int j = 0; j < 25; j++) {
            float pu = rlf(uu, KB + j);
            if ((j & 3) == 0)      s0 = fmaf(ktw[j], pu, s0);
            else if ((j & 3) == 1) s1 = fmaf(ktw[j], pu, s1);
            else if ((j & 3) == 2) s2 = fmaf(ktw[j], pu, s2);
            else                   s3 = fmaf(ktw[j], pu, s3);
        }
        if (lane < HW) SPx[wv][lane] = (s0 + s1) + (s2 + s3);
        __syncthreads();
        float s = SPx[0][ll] + SPx[1][ll];
        vv = (lane < HW) ? bm * __builtin_amdgcn_rcpf(s) : 0.f;
    }

    // logit = T * sum S*P with S = 1 + 0.05*ln(K); split over k-halves
    float ssp = 0.f;
#pragma unroll
    for (int j = 0; j < 25; j++) {
        int k = KB + j;
        float term = (k < HW) ? krw[j] * fmaf(0.05f, __logf(krw[j]), 1.f) : 0.f;
        ssp = fmaf(term, rlf(vv, KB + j), ssp);
    }
    if (lane < HW) TP[wv][lane] = ssp;     // reuse TP for ssum exchange
    __syncthreads();
    float sstot = TP[0][ll] + TP[1][ll];
    float contrib = (lane < HW) ? (uu * sstot) : 0.f;
    if (wv == 0) {
        float tot = wsum64(contrib);
        if (lane == 0) ws[OFF_LOGITS + prob] = TEMP * tot;
    }
}

// ---------------- Kernel 5: cross-entropy loss ----------------
__global__ __launch_bounds__(640) void loss_kernel(const float* __restrict__ ws,
                                                   const int* __restrict__ qy,
                                                   float* __restrict__ out) {
    int tid = threadIdx.x;
    float val = 0.f;
    if (tid < NIMG_Q) {
        const float* lg = ws + OFF_LOGITS + tid * PP;
        float l[PP];
        float mx = -1e30f;
#pragma unroll
        for (int p = 0; p < PP; p++) {
            l[p] = lg[p];
            mx = fmaxf(mx, l[p]);
        }
        float se = 0.f;
#pragma unroll
        for (int p = 0; p < PP; p++) se += __expf(l[p] - mx);
        float lse = mx + logf(se);
        int lab = qy[tid];
        val = -(l[lab] - lse);
    }
    __shared__ float red[16];
    float s = wsum64(val);
    if ((tid & 63) == 0) red[tid >> 6] = s;
    __syncthreads();
    if (tid == 0) {
        float tot = 0.f;
#pragma unroll
        for (int w = 0; w < 10; w++) tot += red[w];
        out[0] = tot * (1.0f / NIMG_Q);
    }
}

extern "C" void kernel_launch(void* const* d_in, const int* in_sizes, int n_in,
                              void* d_out, int out_size, void* d_ws, size_t ws_size,
                              hipStream_t stream) {
    const float* sup = (const float*)d_in[0];   // support_xf [8,5,640,7,7]
    const float* qry = (const float*)d_in[1];   // query_xf   [8,75,640,7,7]
    const int* qy = (const int*)d_in[3];        // query_y    [8,75]
    float* ws = (float*)d_ws;
    float* out = (float*)d_out;

    sup_prep<<<NIMG_S, 512, 0, stream>>>(sup, ws);
    qry_prep<<<NIMG_Q, 512, 0, stream>>>(qry, ws);
    margb_kernel<<<NIMG_S * 5, 256, 0, stream>>>(sup, ws);
    gemm_kernel<<<600, 256, 0, stream>>>(ws);
    sinkhorn_kernel<<<NPROB, 128, 0, stream>>>(ws);
    loss_kernel<<<1, 640, 0, stream>>>(ws, qy, out);
}

// Round 12
// 262.924 us; speedup vs baseline: 1.3793x; 1.3793x over previous
//
#include <hip/hip_runtime.h>
#include <math.h>

#define BB 8
#define PP 5
#define QQ 75
#define CC 640
#define HW 49
#define NIMG_Q (BB*QQ)     // 600
#define NIMG_S (BB*PP)     // 40
#define NPROB  (BB*QQ*PP)  // 3000
#define TEMP 12.5f

#define CHUNKS 20          // 640 / 32
#define TROW 16            // u32 per tile row (32 f16)
#define TCH  (HW*TROW)     // 784 u32 per chunk
#define TIMG (CHUNKS*TCH)  // 15680 u32 per image
#define SROW 25            // u32 per S row (50 f16, last is zero pad)
#define SPROB (HW*SROW)    // 1225 u32 per problem

// workspace layout (u32/float offsets); total ~14.48M words = 57.9 MB
#define OFF_SGAP   0
#define OFF_QGAP   (OFF_SGAP  + NIMG_S*CC)
#define OFF_SMEAN  (OFF_QGAP  + NIMG_Q*CC)
#define OFF_SINV   (OFF_SMEAN + NIMG_S*HW)
#define OFF_QMEAN  (OFF_SINV  + NIMG_S*HW)
#define OFF_QINV   (OFF_QMEAN + NIMG_Q*HW)
#define OFF_MARGA  (OFF_QINV  + NIMG_Q*HW)
#define OFF_MARGB  (OFF_MARGA + NPROB*HW)
#define OFF_QT     (OFF_MARGB + NPROB*HW)          // query f16 tiles
#define OFF_ST     (OFF_QT    + NIMG_Q*TIMG)       // support f16 tiles
#define OFF_S16    (OFF_ST    + NIMG_S*TIMG)       // S matrices, f16 packed
#define OFF_LOGITS (OFF_S16   + NPROB*SPROB)

typedef _Float16 f16x8 __attribute__((ext_vector_type(8)));
typedef float f32x4 __attribute__((ext_vector_type(4)));
#define MFMAH __builtin_amdgcn_mfma_f32_16x16x32_f16

__device__ __forceinline__ float wsum64(float v) {
#pragma unroll
    for (int off = 32; off > 0; off >>= 1) v += __shfl_xor(v, off, 64);
    return v;
}
__device__ __forceinline__ float rlf(float x, int l) {
    return __int_as_float(__builtin_amdgcn_readlane(__float_as_int(x), l));
}
__device__ __forceinline__ unsigned packh2(float a, float b) {
    union { _Float16 h[2]; unsigned u; } pk;
    pk.h[0] = (_Float16)a; pk.h[1] = (_Float16)b;
    return pk.u;
}
__device__ __forceinline__ float f16lo(unsigned w) {
    union { unsigned short s; _Float16 h; } u; u.s = (unsigned short)w; return (float)u.h;
}
__device__ __forceinline__ float f16hi(unsigned w) {
    union { unsigned short s; _Float16 h; } u; u.s = (unsigned short)(w >> 16); return (float)u.h;
}

// ---------------- Kernel 1: support prep ----------------
// R6 structure: R4 flow + waves_per_eu(4,4) + deep load batches (MLP).
__global__ __launch_bounds__(512) __attribute__((amdgpu_waves_per_eu(4, 4)))
void sup_prep(const float* __restrict__ sup, float* __restrict__ ws) {
    int img = blockIdx.x;
    int tid = threadIdx.x;
    int lane = tid & 63;
    int wv = tid >> 6;                 // 0..7
    const float* X = sup + (size_t)img * CC * HW;
    float* gap = ws + OFF_SGAP + img * CC;

    __shared__ float cs_p[8][52], sq_p[8][52];
    __shared__ float muL[52], invL[52];
    float cs = 0.f, sq = 0.f;
    if (lane < HW) {
        for (int c8 = wv * 80; c8 < wv * 80 + 80; c8 += 8) {
            float v[8];
#pragma unroll
            for (int j = 0; j < 8; j++) v[j] = X[(c8 + j) * HW + lane];
#pragma unroll
            for (int j = 0; j < 8; j++) {
                cs += v[j];
                sq = fmaf(v[j], v[j], sq);
            }
        }
    }
    if (lane < 52) {
        cs_p[wv][lane] = (lane < HW) ? cs : 0.f;
        sq_p[wv][lane] = (lane < HW) ? sq : 0.f;
    }
    __syncthreads();
    if (wv == 0 && lane < HW) {
        float c4 = 0.f, s4 = 0.f;
#pragma unroll
        for (int w = 0; w < 8; w++) { c4 += cs_p[w][lane]; s4 += sq_p[w][lane]; }
        float mu = c4 * (1.0f / CC);
        float nsq = fmaxf(s4 - c4 * c4 * (1.0f / CC), 0.f);
        float inv = 1.0f / fmaxf(sqrtf(nsq), 1e-8f);
        ws[OFF_SMEAN + img * HW + lane] = mu;
        ws[OFF_SINV + img * HW + lane] = inv;
        muL[lane] = mu;
        invL[lane] = inv;
    }
    // pass B: GAP (L1/L2-hot re-read), 8-deep batched, m-order preserved
    for (int c = tid; c < CC; c += 512) {
        const float* row = X + c * HW;
        float s = 0.f;
#pragma unroll
        for (int g = 0; g < 6; g++) {
            float rv[8];
#pragma unroll
            for (int j = 0; j < 8; j++) rv[j] = row[g * 8 + j];
#pragma unroll
            for (int j = 0; j < 8; j++) s += rv[j];
        }
        s += row[48];
        gap[c] = s * (1.0f / HW);
    }
    __syncthreads();
    // pass C: f16 tiles, 32-deep batched loads + uint4 stores
    unsigned* T = (unsigned*)ws + OFF_ST + (size_t)img * TIMG;
    int m = lane;
    if (m < HW) {
        float mu = muL[m], inv = invL[m];
        for (int t = wv; t < CHUNKS; t += 8) {
            float va[32];
#pragma unroll
            for (int j = 0; j < 32; j++) va[j] = X[(t * 32 + j) * HW + m];
            unsigned pk[16];
#pragma unroll
            for (int w = 0; w < 16; w++)
                pk[w] = packh2((va[2 * w] - mu) * inv, (va[2 * w + 1] - mu) * inv);
            uint4* dst = (uint4*)(T + t * TCH + m * TROW);
#pragma unroll
            for (int u = 0; u < 4; u++)
                dst[u] = make_uint4(pk[4 * u], pk[4 * u + 1], pk[4 * u + 2], pk[4 * u + 3]);
        }
    }
}

// ---------------- Kernel 2: query prep ----------------
// sg panel (5x640 = 12.8 KB) staged in LDS once; pass-A 16-deep batched.
__global__ __launch_bounds__(512) __attribute__((amdgpu_waves_per_eu(4, 4)))
void qry_prep(const float* __restrict__ qry, float* __restrict__ ws) {
    int img = blockIdx.x;            // = bq
    int b = img / QQ;
    int tid = threadIdx.x;
    int lane = tid & 63;
    int wv = tid >> 6;               // 0..7
    const float* X = qry + (size_t)img * CC * HW;
    const float* sg = ws + OFF_SGAP + b * PP * CC;
    float* gap = ws + OFF_QGAP + img * CC;

    __shared__ float XSG[PP * CC];   // 12.8 KB
    __shared__ float cs_p[8][52], sq_p[8][52];
    __shared__ float part[8][PP][52];
    __shared__ float muL[52], invL[52];

    for (int i = tid; i < PP * CC / 4; i += 512)
        ((float4*)XSG)[i] = ((const float4*)sg)[i];
    __syncthreads();

    float cs = 0.f, sq = 0.f;
    float acc[PP] = {0.f, 0.f, 0.f, 0.f, 0.f};
    if (lane < HW) {
        for (int c8 = wv * 80; c8 < wv * 80 + 80; c8 += 16) {
            float v[16];
#pragma unroll
            for (int j = 0; j < 16; j++) v[j] = X[(c8 + j) * HW + lane];
#pragma unroll
            for (int j = 0; j < 16; j++) {
                cs += v[j];
                sq = fmaf(v[j], v[j], sq);
            }
#pragma unroll
            for (int p = 0; p < PP; p++) {
                float a = acc[p];
#pragma unroll
                for (int qv = 0; qv < 4; qv++) {
                    float4 g0 = *(const float4*)&XSG[p * CC + c8 + 4 * qv];
                    a = fmaf(v[4 * qv + 0], g0.x, a);
                    a = fmaf(v[4 * qv + 1], g0.y, a);
                    a = fmaf(v[4 * qv + 2], g0.z, a);
                    a = fmaf(v[4 * qv + 3], g0.w, a);
                }
                acc[p] = a;
            }
        }
    }
    if (lane < 52) {
        cs_p[wv][lane] = (lane < HW) ? cs : 0.f;
        sq_p[wv][lane] = (lane < HW) ? sq : 0.f;
#pragma unroll
        for (int p = 0; p < PP; p++) part[wv][p][lane] = (lane < HW) ? acc[p] : 0.f;
    }
    __syncthreads();
    if (wv == 0) {
        if (lane < HW) {
            float c4 = 0.f, s4 = 0.f;
#pragma unroll
            for (int w = 0; w < 8; w++) { c4 += cs_p[w][lane]; s4 += sq_p[w][lane]; }
            float mu = c4 * (1.0f / CC);
            float nsq = fmaxf(s4 - c4 * c4 * (1.0f / CC), 0.f);
            float inv = 1.0f / fmaxf(sqrtf(nsq), 1e-8f);
            ws[OFF_QMEAN + img * HW + lane] = mu;
            ws[OFF_QINV + img * HW + lane] = inv;
            muL[lane] = mu;
            invL[lane] = inv;
        }
#pragma unroll
        for (int p = 0; p < PP; p++) {
            float a = 0.f;
            if (lane < 52) {
#pragma unroll
                for (int w = 0; w < 8; w++) a += part[w][p][lane];
            }
            float w = (lane < HW) ? (fmaxf(a, 0.f) + 1.01e-3f) : 0.f;
            float s = wsum64(w);
            if (lane < HW) ws[OFF_MARGA + (img * PP + p) * HW + lane] = w / s;
        }
    }
    // pass B: GAP, 8-deep batched
    for (int c = tid; c < CC; c += 512) {
        const float* row = X + c * HW;
        float s = 0.f;
#pragma unroll
        for (int g = 0; g < 6; g++) {
            float rv[8];
#pragma unroll
            for (int j = 0; j < 8; j++) rv[j] = row[g * 8 + j];
#pragma unroll
            for (int j = 0; j < 8; j++) s += rv[j];
        }
        s += row[48];
        gap[c] = s * (1.0f / HW);
    }
    __syncthreads();
    // pass C: f16 tiles, 32-deep batched
    unsigned* T = (unsigned*)ws + OFF_QT + (size_t)img * TIMG;
    int m = lane;
    if (m < HW) {
        float mu = muL[m], inv = invL[m];
        for (int t = wv; t < CHUNKS; t += 8) {
            float va[32];
#pragma unroll
            for (int j = 0; j < 32; j++) va[j] = X[(t * 32 + j) * HW + m];
            unsigned pk[16];
#pragma unroll
            for (int w = 0; w < 16; w++)
                pk[w] = packh2((va[2 * w] - mu) * inv, (va[2 * w + 1] - mu) * inv);
            uint4* dst = (uint4*)(T + t * TCH + m * TROW);
#pragma unroll
            for (int u = 0; u < 4; u++)
                dst[u] = make_uint4(pk[4 * u], pk[4 * u + 1], pk[4 * u + 2], pk[4 * u + 3]);
        }
    }
}

// ---------------- Kernel 3: fused gemm (blocks 0..599) + margb (600..799) -----
// R11: margb and gemm are mutually independent (margb: qgap+supX -> MARGB;
// gemm: tiles -> S16; both consumed only by sinkhorn). Serially each
// under-fills the machine (200 / 600 blocks); merged = 800 blocks in one
// dispatch, one less launch gap. Per-thread arithmetic identical in both
// paths -> bitwise-identical outputs. LDS: margb carves QG (38.4 KB) +
// part (12.5 KB) from the gemm's 62.7 KB buffer.
__global__ __launch_bounds__(256, 2) void mgemm_kernel(const float* __restrict__ sup,
                                                       float* __restrict__ ws) {
    __shared__ unsigned LDSU[CHUNKS * TCH];   // 15680 u32 = 62.7 KB

    int g = blockIdx.x;
    int tid = threadIdx.x;
    int lane = tid & 63;
    int wv = tid >> 6;

    if (g < 600) {
        // ================= GEMM path (identical to R6) =================
        int xcd = g & 7;
        int k = g >> 3;                    // 0..74
        int p = k % 5;
        int gidx = xcd + 8 * (k / 5);      // 0..119  (b,qg) group
        int b = gidx / 15;
        int qg = gidx - b * 15;            // queries qg*5 .. qg*5+4
        int lrow = lane & 15;
        int quad = lane >> 4;

        const unsigned* Bt = (const unsigned*)ws + OFF_ST + (size_t)(b * PP + p) * TIMG;
        for (int idx = tid; idx < CHUNKS * HW * 4; idx += 256) {   // 3920 x 16B
            int r = idx >> 2;
            int q = idx & 3;
            int t = r / 49;
            int n = r - t * 49;
            uint4 v = *(const uint4*)(Bt + (idx << 2));
            *(uint4*)(&LDSU[t * TCH + n * 16 + ((q ^ ((n >> 1) & 3)) << 2)]) = v;
        }
        __syncthreads();

        int bof[4];
#pragma unroll
        for (int nt = 0; nt < 4; nt++) {
            int n = 16 * nt + lrow;
            if (n > 48) n = 48;
            bof[nt] = n * 16 + ((quad ^ ((n >> 1) & 3)) << 2);
        }

        const unsigned* Aq = (const unsigned*)ws + OFF_QT + (size_t)(b * QQ + qg * 5) * TIMG;
        int arow = (16 * wv + lrow) * TROW + quad * 4;

        f32x4 acc[5][4];
#pragma unroll
        for (int qi = 0; qi < 5; qi++)
#pragma unroll
            for (int nt = 0; nt < 4; nt++) acc[qi][nt] = (f32x4){0.f, 0.f, 0.f, 0.f};

#pragma unroll 2
        for (int t = 0; t < CHUNKS; t++) {
            f16x8 bfr[4];
#pragma unroll
            for (int nt = 0; nt < 4; nt++)
                bfr[nt] = *(const f16x8*)(&LDSU[t * TCH + bof[nt]]);
#pragma unroll
            for (int qi = 0; qi < 5; qi++) {
                f16x8 a = *(const f16x8*)(Aq + (size_t)qi * TIMG + t * TCH + arow);
#pragma unroll
                for (int nt = 0; nt < 4; nt++)
                    acc[qi][nt] = MFMAH(a, bfr[nt], acc[qi][nt], 0, 0, 0);
            }
        }

        __syncthreads();                       // all B reads done
        float* S_lds = (float*)LDSU;           // 5 * 49*53 = 12985 f32 < 15680
        // C/D layout: col = lane&15, row = quad*4 + reg (dtype-independent, m89)
#pragma unroll
        for (int qi = 0; qi < 5; qi++)
#pragma unroll
            for (int nt = 0; nt < 4; nt++)
#pragma unroll
                for (int r = 0; r < 4; r++) {
                    int mm = 16 * wv + quad * 4 + r;
                    int nn = 16 * nt + lrow;
                    if (mm < HW && nn < HW) S_lds[qi * 2597 + mm * 53 + nn] = acc[qi][nt][r];
                }
        __syncthreads();

        for (int qi = 0; qi < 5; qi++) {
            int prob = (b * QQ + qg * 5 + qi) * PP + p;
            unsigned* Sp = (unsigned*)ws + OFF_S16 + (size_t)prob * SPROB;
            const float* Sl = S_lds + qi * 2597;
            for (int idx = tid; idx < SPROB; idx += 256) {
                int row = idx / SROW;
                int w = idx - row * SROW;
                int n0 = 2 * w;
                float v0 = Sl[row * 53 + n0];
                float v1 = (n0 + 1 < HW) ? Sl[row * 53 + n0 + 1] : 0.f;
                Sp[idx] = packh2(v0, v1);
            }
        }
    } else {
        // ================= margb path (identical math to R6) =================
        int id = g - 600;
        int qc = id % 5;
        int bp = id / 5;
        int b = bp / PP;
        int p = bp % PP;
        const float* X = sup + (size_t)bp * CC * HW;
        const float* qg = ws + OFF_QGAP + (b * QQ + qc * 15) * CC;

        float* QG = (float*)LDSU;                                   // 15*640 = 9600 f
        float (*part)[15][52] = (float (*)[15][52])((float*)LDSU + 15 * CC); // +3120 f
        for (int i = tid; i < 15 * CC / 4; i += 256)
            ((float4*)QG)[i] = ((const float4*)qg)[i];
        __syncthreads();

        float acc[15];
#pragma unroll
        for (int i = 0; i < 15; i++) acc[i] = 0.f;
        if (lane < HW) {
            for (int c8 = wv * 160; c8 < wv * 160 + 160; c8 += 8) {
                float sv[8];
#pragma unroll
                for (int j = 0; j < 8; j++) sv[j] = X[(c8 + j) * HW + lane];
#pragma unroll
                for (int qq = 0; qq < 15; qq++) {
                    float4 g0 = *(const float4*)&QG[qq * CC + c8];
                    float4 g1 = *(const float4*)&QG[qq * CC + c8 + 4];
                    float a = acc[qq];
                    a = fmaf(sv[0], g0.x, a); a = fmaf(sv[1], g0.y, a);
                    a = fmaf(sv[2], g0.z, a); a = fmaf(sv[3], g0.w, a);
                    a = fmaf(sv[4], g1.x, a); a = fmaf(sv[5], g1.y, a);
                    a = fmaf(sv[6], g1.z, a); a = fmaf(sv[7], g1.w, a);
                    acc[qq] = a;
                }
            }
        }
        __syncthreads();   // order the LDS-write phase uniformly across waves
        if (lane < 52) {
#pragma unroll
            for (int qq = 0; qq < 15; qq++) part[wv][qq][lane] = (lane < HW) ? acc[qq] : 0.f;
        }
        __syncthreads();
        if (wv == 0) {
#pragma unroll
            for (int qq = 0; qq < 15; qq++) {
                float a = 0.f;
                if (lane < 52)
                    a = part[0][qq][lane] + part[1][qq][lane] + part[2][qq][lane] + part[3][qq][lane];
                int q = qc * 15 + qq;
                float w = (lane < HW) ? (fmaxf(a, 0.f) + 1.01e-3f) : 0.f;
                float s = wsum64(w);
                if (lane < HW) ws[OFF_MARGB + ((b * QQ + q) * PP + p) * HW + lane] = w / s;
            }
        }
    }
}

// ---------------- Kernel 4b: Sinkhorn + logit, one wave per problem ----------
// R11: reverted to the R6 all-register structure (best measured: 56.6us).
// Three structural alternatives all failed: LDS-KT (R7, 72us: DS latency
// chain), opq VGPR-pinning (R9, 57us: no change -- values live in unified-
// file AGPR side), 2-wave split (R10, 140us: 96 barriers on the critical
// chain). ~335 VALU ops/iter vs ~205 clean is register-file/issue overhead
// this structure cannot avoid; treat 57us as the practical floor.
#define FOR12(M) M(0) M(1) M(2) M(3) M(4) M(5) M(6) M(7) M(8) M(9) M(10) M(11)
#define KEXPF(s) __expf(fmaf(20.f, (s), -20.f))

__global__ __launch_bounds__(64)
__attribute__((amdgpu_waves_per_eu(3, 3)))
void sinkhorn_kernel(float* __restrict__ ws) {
    int prob = blockIdx.x;
    int lane = threadIdx.x;
    const unsigned* Sp = (const unsigned*)ws + OFF_S16 + (size_t)prob * SPROB;

    float am = 0.f, bm = 0.f;
    if (lane < HW) {
        am = ws[OFF_MARGA + prob * HW + lane];
        bm = ws[OFF_MARGB + prob * HW + lane];
    }
    int ll = (lane < HW) ? lane : 48;
    const unsigned* rbase = Sp + ll * SROW;       // row ll of S (f16 pairs)
    int wof = ll >> 1;
    int sh = (ll & 1) * 16;

    float4 kr0, kr1, kr2, kr3, kr4, kr5, kr6, kr7, kr8, kr9, kr10, kr11;
    float4 kt0, kt1, kt2, kt3, kt4, kt5, kt6, kt7, kt8, kt9, kt10, kt11;
    float kr12x, kt12x;
#define KIR(g) { unsigned w0 = rbase[2*(g)]; unsigned w1 = rbase[2*(g)+1];  \
    kr##g = make_float4(KEXPF(f16lo(w0)), KEXPF(f16hi(w0)),                 \
                        KEXPF(f16lo(w1)), KEXPF(f16hi(w1))); }
    FOR12(KIR)
#undef KIR
    kr12x = KEXPF(f16lo(rbase[24]));
#define KIT(g) { \
    float s0 = f16lo((Sp[(4*(g)+0)*SROW + wof] >> sh) & 0xFFFFu);           \
    float s1 = f16lo((Sp[(4*(g)+1)*SROW + wof] >> sh) & 0xFFFFu);           \
    float s2 = f16lo((Sp[(4*(g)+2)*SROW + wof] >> sh) & 0xFFFFu);           \
    float s3 = f16lo((Sp[(4*(g)+3)*SROW + wof] >> sh) & 0xFFFFu);           \
    kt##g = make_float4(KEXPF(s0), KEXPF(s1), KEXPF(s2), KEXPF(s3)); }
    FOR12(KIT)
#undef KIT
    kt12x = KEXPF(f16lo((Sp[48 * SROW + wof] >> sh) & 0xFFFFu));

    float vv = (lane < HW) ? 1.f : 0.f;
    float uu = 0.f;

#pragma unroll 1
    for (int it = 0; it < 48; it++) {
        float t0 = 0.f, t1 = 0.f, t2 = 0.f, t3 = 0.f;
#define RS(g) { t0 = fmaf(kr##g.x, rlf(vv, 4*(g)+0), t0);                   \
                t1 = fmaf(kr##g.y, rlf(vv, 4*(g)+1), t1);                   \
                t2 = fmaf(kr##g.z, rlf(vv, 4*(g)+2), t2);                   \
                t3 = fmaf(kr##g.w, rlf(vv, 4*(g)+3), t3); }
        FOR12(RS)
#undef RS
        t0 = fmaf(kr12x, rlf(vv, 48), t0);
        float t = (t0 + t1) + (t2 + t3);
        uu = am * __builtin_amdgcn_rcpf(t);

        float s0 = 0.f, s1 = 0.f, s2 = 0.f, s3 = 0.f;
#define CS(g) { s0 = fmaf(kt##g.x, rlf(uu, 4*(g)+0), s0);                   \
                s1 = fmaf(kt##g.y, rlf(uu, 4*(g)+1), s1);                   \
                s2 = fmaf(kt##g.z, rlf(uu, 4*(g)+2), s2);                   \
                s3 = fmaf(kt##g.w, rlf(uu, 4*(g)+3), s3); }
        FOR12(CS)
#undef CS
        s0 = fmaf(kt12x, rlf(uu, 48), s0);
        float s = (s0 + s1) + (s2 + s3);
        vv = bm * __builtin_amdgcn_rcpf(s);
    }

    // logit = T * sum S*P with S = 1 + 0.05*ln(K)
    float ssum = 0.f;
#define FS(g) {                                                             \
    ssum = fmaf(kr##g.x * fmaf(0.05f, __logf(kr##g.x), 1.f), rlf(vv, 4*(g)+0), ssum); \
    ssum = fmaf(kr##g.y * fmaf(0.05f, __logf(kr##g.y), 1.f), rlf(vv, 4*(g)+1), ssum); \
    ssum = fmaf(kr##g.z * fmaf(0.05f, __logf(kr##g.z), 1.f), rlf(vv, 4*(g)+2), ssum); \
    ssum = fmaf(kr##g.w * fmaf(0.05f, __logf(kr##g.w), 1.f), rlf(vv, 4*(g)+3), ssum); }
    FOR12(FS)
#undef FS
    ssum = fmaf(kr12x * fmaf(0.05f, __logf(kr12x), 1.f), rlf(vv, 48), ssum);
    float contrib = (lane < HW) ? (uu * ssum) : 0.f;
    float tot = wsum64(contrib);
    if (lane == 0) ws[OFF_LOGITS + prob] = TEMP * tot;
}

// ---------------- Kernel 5: cross-entropy loss ----------------
__global__ __launch_bounds__(640) void loss_kernel(const float* __restrict__ ws,
                                                   const int* __restrict__ qy,
                                                   float* __restrict__ out) {
    int tid = threadIdx.x;
    float val = 0.f;
    if (tid < NIMG_Q) {
        const float* lg = ws + OFF_LOGITS + tid * PP;
        float l[PP];
        float mx = -1e30f;
#pragma unroll
        for (int p = 0; p < PP; p++) {
            l[p] = lg[p];
            mx = fmaxf(mx, l[p]);
        }
        float se = 0.f;
#pragma unroll
        for (int p = 0; p < PP; p++) se += __expf(l[p] - mx);
        float lse = mx + logf(se);
        int lab = qy[tid];
        val = -(l[lab] - lse);
    }
    __shared__ float red[16];
    float s = wsum64(val);
    if ((tid & 63) == 0) red[tid >> 6] = s;
    __syncthreads();
    if (tid == 0) {
        float tot = 0.f;
#pragma unroll
        for (int w = 0; w < 10; w++) tot += red[w];
        out[0] = tot * (1.0f / NIMG_Q);
    }
}

extern "C" void kernel_launch(void* const* d_in, const int* in_sizes, int n_in,
                              void* d_out, int out_size, void* d_ws, size_t ws_size,
                              hipStream_t stream) {
    const float* sup = (const float*)d_in[0];   // support_xf [8,5,640,7,7]
    const float* qry = (const float*)d_in[1];   // query_xf   [8,75,640,7,7]
    const int* qy = (const int*)d_in[3];        // query_y    [8,75]
    float* ws = (float*)d_ws;
    float* out = (float*)d_out;

    sup_prep<<<NIMG_S, 512, 0, stream>>>(sup, ws);
    qry_prep<<<NIMG_Q, 512, 0, stream>>>(qry, ws);
    mgemm_kernel<<<800, 256, 0, stream>>>(sup, ws);
    sinkhorn_kernel<<<NPROB, 64, 0, stream>>>(ws);
    loss_kernel<<<1, 640, 0, stream>>>(ws, qy, out);
}

// Round 13
// 258.416 us; speedup vs baseline: 1.4034x; 1.0174x over previous
//
#include <hip/hip_runtime.h>
#include <math.h>

#define BB 8
#define PP 5
#define QQ 75
#define CC 640
#define HW 49
#define NIMG_Q (BB*QQ)     // 600
#define NIMG_S (BB*PP)     // 40
#define NPROB  (BB*QQ*PP)  // 3000
#define TEMP 12.5f

#define CHUNKS 20          // 640 / 32
#define TROW 16            // u32 per tile row (32 f16)
#define TCH  (HW*TROW)     // 784 u32 per chunk
#define TIMG (CHUNKS*TCH)  // 15680 u32 per image
#define SROW 25            // u32 per S row (50 f16, last is zero pad)
#define SPROB (HW*SROW)    // 1225 u32 per problem

// workspace layout (u32/float offsets); total ~14.48M words = 57.9 MB
#define OFF_SGAP   0
#define OFF_QGAP   (OFF_SGAP  + NIMG_S*CC)
#define OFF_SMEAN  (OFF_QGAP  + NIMG_Q*CC)
#define OFF_SINV   (OFF_SMEAN + NIMG_S*HW)
#define OFF_QMEAN  (OFF_SINV  + NIMG_S*HW)
#define OFF_QINV   (OFF_QMEAN + NIMG_Q*HW)
#define OFF_MARGA  (OFF_QINV  + NIMG_Q*HW)
#define OFF_MARGB  (OFF_MARGA + NPROB*HW)
#define OFF_QT     (OFF_MARGB + NPROB*HW)          // query f16 tiles
#define OFF_ST     (OFF_QT    + NIMG_Q*TIMG)       // support f16 tiles
#define OFF_S16    (OFF_ST    + NIMG_S*TIMG)       // S matrices, f16 packed
#define OFF_LOGITS (OFF_S16   + NPROB*SPROB)

typedef _Float16 f16x8 __attribute__((ext_vector_type(8)));
typedef float f32x4 __attribute__((ext_vector_type(4)));
#define MFMAH __builtin_amdgcn_mfma_f32_16x16x32_f16

__device__ __forceinline__ float wsum64(float v) {
#pragma unroll
    for (int off = 32; off > 0; off >>= 1) v += __shfl_xor(v, off, 64);
    return v;
}
__device__ __forceinline__ float rlf(float x, int l) {
    return __int_as_float(__builtin_amdgcn_readlane(__float_as_int(x), l));
}
__device__ __forceinline__ unsigned packh2(float a, float b) {
    union { _Float16 h[2]; unsigned u; } pk;
    pk.h[0] = (_Float16)a; pk.h[1] = (_Float16)b;
    return pk.u;
}
__device__ __forceinline__ float f16lo(unsigned w) {
    union { unsigned short s; _Float16 h; } u; u.s = (unsigned short)w; return (float)u.h;
}
__device__ __forceinline__ float f16hi(unsigned w) {
    union { unsigned short s; _Float16 h; } u; u.s = (unsigned short)(w >> 16); return (float)u.h;
}

// ---------------- Kernel 0: support GAP pre-pass ----------------
// R13: qry_prep's only dependency on sup_prep is the SGAP panel. Compute it
// in a tiny pre-kernel (5 MB read, ~3-5us) so the rest of sup_prep can run
// CONCURRENTLY with qry_prep in one merged dispatch. Identical 8-deep
// batched sum order -> bitwise-identical SGAP.
__global__ __launch_bounds__(256) void sgap_kernel(const float* __restrict__ sup,
                                                   float* __restrict__ ws) {
    int img = blockIdx.x;              // 0..39
    int tid = threadIdx.x;
    const float* X = sup + (size_t)img * CC * HW;
    float* gap = ws + OFF_SGAP + img * CC;
    for (int c = tid; c < CC; c += 256) {
        const float* row = X + c * HW;
        float s = 0.f;
#pragma unroll
        for (int g = 0; g < 6; g++) {
            float rv[8];
#pragma unroll
            for (int j = 0; j < 8; j++) rv[j] = row[g * 8 + j];
#pragma unroll
            for (int j = 0; j < 8; j++) s += rv[j];
        }
        s += row[48];
        gap[c] = s * (1.0f / HW);
    }
}

// ---------------- Kernel 1: merged prep: qry (0..599) + sup rest (600..639) --
// qry path: identical to R12 qry_prep. sup path: R12 sup_prep minus pass B
// (gap moved to sgap_kernel); barrier structure uniform per path.
__global__ __launch_bounds__(512) __attribute__((amdgpu_waves_per_eu(4, 4)))
void prep_kernel(const float* __restrict__ sup, const float* __restrict__ qry,
                 float* __restrict__ ws) {
    int g = blockIdx.x;
    int tid = threadIdx.x;
    int lane = tid & 63;
    int wv = tid >> 6;               // 0..7

    __shared__ float XSG[PP * CC];   // 12.8 KB (qry path only)
    __shared__ float cs_p[8][52], sq_p[8][52];
    __shared__ float part[8][PP][52];
    __shared__ float muL[52], invL[52];

    if (g < 600) {
        // ================= query path (identical to R12) =================
        int img = g;
        int b = img / QQ;
        const float* X = qry + (size_t)img * CC * HW;
        const float* sg = ws + OFF_SGAP + b * PP * CC;
        float* gap = ws + OFF_QGAP + img * CC;

        for (int i = tid; i < PP * CC / 4; i += 512)
            ((float4*)XSG)[i] = ((const float4*)sg)[i];
        __syncthreads();

        float cs = 0.f, sq = 0.f;
        float acc[PP] = {0.f, 0.f, 0.f, 0.f, 0.f};
        if (lane < HW) {
            for (int c8 = wv * 80; c8 < wv * 80 + 80; c8 += 16) {
                float v[16];
#pragma unroll
                for (int j = 0; j < 16; j++) v[j] = X[(c8 + j) * HW + lane];
#pragma unroll
                for (int j = 0; j < 16; j++) {
                    cs += v[j];
                    sq = fmaf(v[j], v[j], sq);
                }
#pragma unroll
                for (int p = 0; p < PP; p++) {
                    float a = acc[p];
#pragma unroll
                    for (int qv = 0; qv < 4; qv++) {
                        float4 g0 = *(const float4*)&XSG[p * CC + c8 + 4 * qv];
                        a = fmaf(v[4 * qv + 0], g0.x, a);
                        a = fmaf(v[4 * qv + 1], g0.y, a);
                        a = fmaf(v[4 * qv + 2], g0.z, a);
                        a = fmaf(v[4 * qv + 3], g0.w, a);
                    }
                    acc[p] = a;
                }
            }
        }
        if (lane < 52) {
            cs_p[wv][lane] = (lane < HW) ? cs : 0.f;
            sq_p[wv][lane] = (lane < HW) ? sq : 0.f;
#pragma unroll
            for (int p = 0; p < PP; p++) part[wv][p][lane] = (lane < HW) ? acc[p] : 0.f;
        }
        __syncthreads();
        if (wv == 0) {
            if (lane < HW) {
                float c4 = 0.f, s4 = 0.f;
#pragma unroll
                for (int w = 0; w < 8; w++) { c4 += cs_p[w][lane]; s4 += sq_p[w][lane]; }
                float mu = c4 * (1.0f / CC);
                float nsq = fmaxf(s4 - c4 * c4 * (1.0f / CC), 0.f);
                float inv = 1.0f / fmaxf(sqrtf(nsq), 1e-8f);
                ws[OFF_QMEAN + img * HW + lane] = mu;
                ws[OFF_QINV + img * HW + lane] = inv;
                muL[lane] = mu;
                invL[lane] = inv;
            }
#pragma unroll
            for (int p = 0; p < PP; p++) {
                float a = 0.f;
                if (lane < 52) {
#pragma unroll
                    for (int w = 0; w < 8; w++) a += part[w][p][lane];
                }
                float w = (lane < HW) ? (fmaxf(a, 0.f) + 1.01e-3f) : 0.f;
                float s = wsum64(w);
                if (lane < HW) ws[OFF_MARGA + (img * PP + p) * HW + lane] = w / s;
            }
        }
        // pass B: GAP, 8-deep batched
        for (int c = tid; c < CC; c += 512) {
            const float* row = X + c * HW;
            float s = 0.f;
#pragma unroll
            for (int gg = 0; gg < 6; gg++) {
                float rv[8];
#pragma unroll
                for (int j = 0; j < 8; j++) rv[j] = row[gg * 8 + j];
#pragma unroll
                for (int j = 0; j < 8; j++) s += rv[j];
            }
            s += row[48];
            gap[c] = s * (1.0f / HW);
        }
        __syncthreads();
        // pass C: f16 tiles, 32-deep batched
        unsigned* T = (unsigned*)ws + OFF_QT + (size_t)img * TIMG;
        int m = lane;
        if (m < HW) {
            float mu = muL[m], inv = invL[m];
            for (int t = wv; t < CHUNKS; t += 8) {
                float va[32];
#pragma unroll
                for (int j = 0; j < 32; j++) va[j] = X[(t * 32 + j) * HW + m];
                unsigned pk[16];
#pragma unroll
                for (int w = 0; w < 16; w++)
                    pk[w] = packh2((va[2 * w] - mu) * inv, (va[2 * w + 1] - mu) * inv);
                uint4* dst = (uint4*)(T + t * TCH + m * TROW);
#pragma unroll
                for (int u = 0; u < 4; u++)
                    dst[u] = make_uint4(pk[4 * u], pk[4 * u + 1], pk[4 * u + 2], pk[4 * u + 3]);
            }
        }
    } else {
        // ============ support path: stats + tiles (gap done by sgap) ============
        int img = g - 600;               // 0..39
        const float* X = sup + (size_t)img * CC * HW;

        float cs = 0.f, sq = 0.f;
        if (lane < HW) {
            for (int c8 = wv * 80; c8 < wv * 80 + 80; c8 += 8) {
                float v[8];
#pragma unroll
                for (int j = 0; j < 8; j++) v[j] = X[(c8 + j) * HW + lane];
#pragma unroll
                for (int j = 0; j < 8; j++) {
                    cs += v[j];
                    sq = fmaf(v[j], v[j], sq);
                }
            }
        }
        if (lane < 52) {
            cs_p[wv][lane] = (lane < HW) ? cs : 0.f;
            sq_p[wv][lane] = (lane < HW) ? sq : 0.f;
        }
        __syncthreads();
        if (wv == 0 && lane < HW) {
            float c4 = 0.f, s4 = 0.f;
#pragma unroll
            for (int w = 0; w < 8; w++) { c4 += cs_p[w][lane]; s4 += sq_p[w][lane]; }
            float mu = c4 * (1.0f / CC);
            float nsq = fmaxf(s4 - c4 * c4 * (1.0f / CC), 0.f);
            float inv = 1.0f / fmaxf(sqrtf(nsq), 1e-8f);
            ws[OFF_SMEAN + img * HW + lane] = mu;
            ws[OFF_SINV + img * HW + lane] = inv;
            muL[lane] = mu;
            invL[lane] = inv;
        }
        __syncthreads();                   // muL/invL visible before pass C
        unsigned* T = (unsigned*)ws + OFF_ST + (size_t)img * TIMG;
        int m = lane;
        if (m < HW) {
            float mu = muL[m], inv = invL[m];
            for (int t = wv; t < CHUNKS; t += 8) {
                float va[32];
#pragma unroll
                for (int j = 0; j < 32; j++) va[j] = X[(t * 32 + j) * HW + m];
                unsigned pk[16];
#pragma unroll
                for (int w = 0; w < 16; w++)
                    pk[w] = packh2((va[2 * w] - mu) * inv, (va[2 * w + 1] - mu) * inv);
                uint4* dst = (uint4*)(T + t * TCH + m * TROW);
#pragma unroll
                for (int u = 0; u < 4; u++)
                    dst[u] = make_uint4(pk[4 * u], pk[4 * u + 1], pk[4 * u + 2], pk[4 * u + 3]);
            }
        }
    }
}

// ---------------- Kernel 3: fused gemm (blocks 0..599) + margb (600..799) -----
// R11: merged, bitwise-identical outputs; verified R12 (284 -> 263us).
__global__ __launch_bounds__(256, 2) void mgemm_kernel(const float* __restrict__ sup,
                                                       float* __restrict__ ws) {
    __shared__ unsigned LDSU[CHUNKS * TCH];   // 15680 u32 = 62.7 KB

    int g = blockIdx.x;
    int tid = threadIdx.x;
    int lane = tid & 63;
    int wv = tid >> 6;

    if (g < 600) {
        // ================= GEMM path (identical to R6) =================
        int xcd = g & 7;
        int k = g >> 3;                    // 0..74
        int p = k % 5;
        int gidx = xcd + 8 * (k / 5);      // 0..119  (b,qg) group
        int b = gidx / 15;
        int qg = gidx - b * 15;            // queries qg*5 .. qg*5+4
        int lrow = lane & 15;
        int quad = lane >> 4;

        const unsigned* Bt = (const unsigned*)ws + OFF_ST + (size_t)(b * PP + p) * TIMG;
        for (int idx = tid; idx < CHUNKS * HW * 4; idx += 256) {   // 3920 x 16B
            int r = idx >> 2;
            int q = idx & 3;
            int t = r / 49;
            int n = r - t * 49;
            uint4 v = *(const uint4*)(Bt + (idx << 2));
            *(uint4*)(&LDSU[t * TCH + n * 16 + ((q ^ ((n >> 1) & 3)) << 2)]) = v;
        }
        __syncthreads();

        int bof[4];
#pragma unroll
        for (int nt = 0; nt < 4; nt++) {
            int n = 16 * nt + lrow;
            if (n > 48) n = 48;
            bof[nt] = n * 16 + ((quad ^ ((n >> 1) & 3)) << 2);
        }

        const unsigned* Aq = (const unsigned*)ws + OFF_QT + (size_t)(b * QQ + qg * 5) * TIMG;
        int arow = (16 * wv + lrow) * TROW + quad * 4;

        f32x4 acc[5][4];
#pragma unroll
        for (int qi = 0; qi < 5; qi++)
#pragma unroll
            for (int nt = 0; nt < 4; nt++) acc[qi][nt] = (f32x4){0.f, 0.f, 0.f, 0.f};

#pragma unroll 2
        for (int t = 0; t < CHUNKS; t++) {
            f16x8 bfr[4];
#pragma unroll
            for (int nt = 0; nt < 4; nt++)
                bfr[nt] = *(const f16x8*)(&LDSU[t * TCH + bof[nt]]);
#pragma unroll
            for (int qi = 0; qi < 5; qi++) {
                f16x8 a = *(const f16x8*)(Aq + (size_t)qi * TIMG + t * TCH + arow);
#pragma unroll
                for (int nt = 0; nt < 4; nt++)
                    acc[qi][nt] = MFMAH(a, bfr[nt], acc[qi][nt], 0, 0, 0);
            }
        }

        __syncthreads();                       // all B reads done
        float* S_lds = (float*)LDSU;           // 5 * 49*53 = 12985 f32 < 15680
        // C/D layout: col = lane&15, row = quad*4 + reg (dtype-independent, m89)
#pragma unroll
        for (int qi = 0; qi < 5; qi++)
#pragma unroll
            for (int nt = 0; nt < 4; nt++)
#pragma unroll
                for (int r = 0; r < 4; r++) {
                    int mm = 16 * wv + quad * 4 + r;
                    int nn = 16 * nt + lrow;
                    if (mm < HW && nn < HW) S_lds[qi * 2597 + mm * 53 + nn] = acc[qi][nt][r];
                }
        __syncthreads();

        for (int qi = 0; qi < 5; qi++) {
            int prob = (b * QQ + qg * 5 + qi) * PP + p;
            unsigned* Sp = (unsigned*)ws + OFF_S16 + (size_t)prob * SPROB;
            const float* Sl = S_lds + qi * 2597;
            for (int idx = tid; idx < SPROB; idx += 256) {
                int row = idx / SROW;
                int w = idx - row * SROW;
                int n0 = 2 * w;
                float v0 = Sl[row * 53 + n0];
                float v1 = (n0 + 1 < HW) ? Sl[row * 53 + n0 + 1] : 0.f;
                Sp[idx] = packh2(v0, v1);
            }
        }
    } else {
        // ================= margb path (identical math to R6) =================
        int id = g - 600;
        int qc = id % 5;
        int bp = id / 5;
        int b = bp / PP;
        int p = bp % PP;
        const float* X = sup + (size_t)bp * CC * HW;
        const float* qg = ws + OFF_QGAP + (b * QQ + qc * 15) * CC;

        float* QG = (float*)LDSU;                                   // 15*640 = 9600 f
        float (*part)[15][52] = (float (*)[15][52])((float*)LDSU + 15 * CC); // +3120 f
        for (int i = tid; i < 15 * CC / 4; i += 256)
            ((float4*)QG)[i] = ((const float4*)qg)[i];
        __syncthreads();

        float acc[15];
#pragma unroll
        for (int i = 0; i < 15; i++) acc[i] = 0.f;
        if (lane < HW) {
            for (int c8 = wv * 160; c8 < wv * 160 + 160; c8 += 8) {
                float sv[8];
#pragma unroll
                for (int j = 0; j < 8; j++) sv[j] = X[(c8 + j) * HW + lane];
#pragma unroll
                for (int qq = 0; qq < 15; qq++) {
                    float4 g0 = *(const float4*)&QG[qq * CC + c8];
                    float4 g1 = *(const float4*)&QG[qq * CC + c8 + 4];
                    float a = acc[qq];
                    a = fmaf(sv[0], g0.x, a); a = fmaf(sv[1], g0.y, a);
                    a = fmaf(sv[2], g0.z, a); a = fmaf(sv[3], g0.w, a);
                    a = fmaf(sv[4], g1.x, a); a = fmaf(sv[5], g1.y, a);
                    a = fmaf(sv[6], g1.z, a); a = fmaf(sv[7], g1.w, a);
                    acc[qq] = a;
                }
            }
        }
        __syncthreads();   // order the LDS-write phase uniformly across waves
        if (lane < 52) {
#pragma unroll
            for (int qq = 0; qq < 15; qq++) part[wv][qq][lane] = (lane < HW) ? acc[qq] : 0.f;
        }
        __syncthreads();
        if (wv == 0) {
#pragma unroll
            for (int qq = 0; qq < 15; qq++) {
                float a = 0.f;
                if (lane < 52)
                    a = part[0][qq][lane] + part[1][qq][lane] + part[2][qq][lane] + part[3][qq][lane];
                int q = qc * 15 + qq;
                float w = (lane < HW) ? (fmaxf(a, 0.f) + 1.01e-3f) : 0.f;
                float s = wsum64(w);
                if (lane < HW) ws[OFF_MARGB + ((b * QQ + q) * PP + p) * HW + lane] = w / s;
            }
        }
    }
}

// ---------------- Kernel 4b: Sinkhorn + logit, one wave per problem ----------
// R11: reverted to the R6 all-register structure (best measured: 56.6us).
// Three structural alternatives all failed: LDS-KT (R7, 72us: DS latency
// chain), opq VGPR-pinning (R9, 57us: no change -- values live in unified-
// file AGPR side), 2-wave split (R10, 140us: 96 barriers on the critical
// chain). ~335 VALU ops/iter vs ~205 clean is register-file/issue overhead
// this structure cannot avoid; treat 57us as the practical floor.
#define FOR12(M) M(0) M(1) M(2) M(3) M(4) M(5) M(6) M(7) M(8) M(9) M(10) M(11)
#define KEXPF(s) __expf(fmaf(20.f, (s), -20.f))

__global__ __launch_bounds__(64)
__attribute__((amdgpu_waves_per_eu(3, 3)))
void sinkhorn_kernel(float* __restrict__ ws) {
    int prob = blockIdx.x;
    int lane = threadIdx.x;
    const unsigned* Sp = (const unsigned*)ws + OFF_S16 + (size_t)prob * SPROB;

    float am = 0.f, bm = 0.f;
    if (lane < HW) {
        am = ws[OFF_MARGA + prob * HW + lane];
        bm = ws[OFF_MARGB + prob * HW + lane];
    }
    int ll = (lane < HW) ? lane : 48;
    const unsigned* rbase = Sp + ll * SROW;       // row ll of S (f16 pairs)
    int wof = ll >> 1;
    int sh = (ll & 1) * 16;

    float4 kr0, kr1, kr2, kr3, kr4, kr5, kr6, kr7, kr8, kr9, kr10, kr11;
    float4 kt0, kt1, kt2, kt3, kt4, kt5, kt6, kt7, kt8, kt9, kt10, kt11;
    float kr12x, kt12x;
#define KIR(g) { unsigned w0 = rbase[2*(g)]; unsigned w1 = rbase[2*(g)+1];  \
    kr##g = make_float4(KEXPF(f16lo(w0)), KEXPF(f16hi(w0)),                 \
                        KEXPF(f16lo(w1)), KEXPF(f16hi(w1))); }
    FOR12(KIR)
#undef KIR
    kr12x = KEXPF(f16lo(rbase[24]));
#define KIT(g) { \
    float s0 = f16lo((Sp[(4*(g)+0)*SROW + wof] >> sh) & 0xFFFFu);           \
    float s1 = f16lo((Sp[(4*(g)+1)*SROW + wof] >> sh) & 0xFFFFu);           \
    float s2 = f16lo((Sp[(4*(g)+2)*SROW + wof] >> sh) & 0xFFFFu);           \
    float s3 = f16lo((Sp[(4*(g)+3)*SROW + wof] >> sh) & 0xFFFFu);           \
    kt##g = make_float4(KEXPF(s0), KEXPF(s1), KEXPF(s2), KEXPF(s3)); }
    FOR12(KIT)
#undef KIT
    kt12x = KEXPF(f16lo((Sp[48 * SROW + wof] >> sh) & 0xFFFFu));

    float vv = (lane < HW) ? 1.f : 0.f;
    float uu = 0.f;

#pragma unroll 1
    for (int it = 0; it < 48; it++) {
        float t0 = 0.f, t1 = 0.f, t2 = 0.f, t3 = 0.f;
#define RS(g) { t0 = fmaf(kr##g.x, rlf(vv, 4*(g)+0), t0);                   \
                t1 = fmaf(kr##g.y, rlf(vv, 4*(g)+1), t1);                   \
                t2 = fmaf(kr##g.z, rlf(vv, 4*(g)+2), t2);                   \
                t3 = fmaf(kr##g.w, rlf(vv, 4*(g)+3), t3); }
        FOR12(RS)
#undef RS
        t0 = fmaf(kr12x, rlf(vv, 48), t0);
        float t = (t0 + t1) + (t2 + t3);
        uu = am * __builtin_amdgcn_rcpf(t);

        float s0 = 0.f, s1 = 0.f, s2 = 0.f, s3 = 0.f;
#define CS(g) { s0 = fmaf(kt##g.x, rlf(uu, 4*(g)+0), s0);                   \
                s1 = fmaf(kt##g.y, rlf(uu, 4*(g)+1), s1);                   \
                s2 = fmaf(kt##g.z, rlf(uu, 4*(g)+2), s2);                   \
                s3 = fmaf(kt##g.w, rlf(uu, 4*(g)+3), s3); }
        FOR12(CS)
#undef CS
        s0 = fmaf(kt12x, rlf(uu, 48), s0);
        float s = (s0 + s1) + (s2 + s3);
        vv = bm * __builtin_amdgcn_rcpf(s);
    }

    // logit = T * sum S*P with S = 1 + 0.05*ln(K)
    float ssum = 0.f;
#define FS(g) {                                                             \
    ssum = fmaf(kr##g.x * fmaf(0.05f, __logf(kr##g.x), 1.f), rlf(vv, 4*(g)+0), ssum); \
    ssum = fmaf(kr##g.y * fmaf(0.05f, __logf(kr##g.y), 1.f), rlf(vv, 4*(g)+1), ssum); \
    ssum = fmaf(kr##g.z * fmaf(0.05f, __logf(kr##g.z), 1.f), rlf(vv, 4*(g)+2), ssum); \
    ssum = fmaf(kr##g.w * fmaf(0.05f, __logf(kr##g.w), 1.f), rlf(vv, 4*(g)+3), ssum); }
    FOR12(FS)
#undef FS
    ssum = fmaf(kr12x * fmaf(0.05f, __logf(kr12x), 1.f), rlf(vv, 48), ssum);
    float contrib = (lane < HW) ? (uu * ssum) : 0.f;
    float tot = wsum64(contrib);
    if (lane == 0) ws[OFF_LOGITS + prob] = TEMP * tot;
}

// ---------------- Kernel 5: cross-entropy loss ----------------
__global__ __launch_bounds__(640) void loss_kernel(const float* __restrict__ ws,
                                                   const int* __restrict__ qy,
                                                   float* __restrict__ out) {
    int tid = threadIdx.x;
    float val = 0.f;
    if (tid < NIMG_Q) {
        const float* lg = ws + OFF_LOGITS + tid * PP;
        float l[PP];
        float mx = -1e30f;
#pragma unroll
        for (int p = 0; p < PP; p++) {
            l[p] = lg[p];
            mx = fmaxf(mx, l[p]);
        }
        float se = 0.f;
#pragma unroll
        for (int p = 0; p < PP; p++) se += __expf(l[p] - mx);
        float lse = mx + logf(se);
        int lab = qy[tid];
        val = -(l[lab] - lse);
    }
    __shared__ float red[16];
    float s = wsum64(val);
    if ((tid & 63) == 0) red[tid >> 6] = s;
    __syncthreads();
    if (tid == 0) {
        float tot = 0.f;
#pragma unroll
        for (int w = 0; w < 10; w++) tot += red[w];
        out[0] = tot * (1.0f / NIMG_Q);
    }
}

extern "C" void kernel_launch(void* const* d_in, const int* in_sizes, int n_in,
                              void* d_out, int out_size, void* d_ws, size_t ws_size,
                              hipStream_t stream) {
    const float* sup = (const float*)d_in[0];   // support_xf [8,5,640,7,7]
    const float* qry = (const float*)d_in[1];   // query_xf   [8,75,640,7,7]
    const int* qy = (const int*)d_in[3];        // query_y    [8,75]
    float* ws = (float*)d_ws;
    float* out = (float*)d_out;

    sgap_kernel<<<NIMG_S, 256, 0, stream>>>(sup, ws);
    prep_kernel<<<640, 512, 0, stream>>>(sup, qry, ws);
    mgemm_kernel<<<800, 256, 0, stream>>>(sup, ws);
    sinkhorn_kernel<<<NPROB, 64, 0, stream>>>(ws);
    loss_kernel<<<1, 640, 0, stream>>>(ws, qy, out);
}